// Round 9
// baseline (157.404 us; speedup 1.0000x reference)
//
#include <hip/hip_runtime.h>
#include <math.h>

#define BATCH 32
#define NPIX 160
#define LDIM 128
#define OUT_SZ 150        // 160 - 11 + 1
#define PLANE 25600       // 160*160

#define THREADS 256
// work items: stft = 19 prg x 2 pc-halves x 3 c x 32 b = 3648; ssim = 19 tiles x 3 x 32 = 1824
#define N_STFT 3648
#define N_SSIM 1824
#define N_WORK (N_STFT + N_SSIM)   // 5472 = 1824 groups of (2 stft + 1 ssim)

// e^{-i*2pi*k/12}; entries 0 / ±0.5 / ±0.866 / ±1 -> FMAs fold at compile time
__device__ constexpr float TWC[12] = { 1.f, 0.86602540f, 0.5f, 0.f, -0.5f, -0.86602540f,
                                      -1.f,-0.86602540f,-0.5f, 0.f,  0.5f,  0.86602540f};
__device__ constexpr float TWS[12] = { 0.f,-0.5f,-0.86602540f,-1.f,-0.86602540f,-0.5f,
                                       0.f, 0.5f, 0.86602540f, 1.f, 0.86602540f, 0.5f};

__device__ constexpr float GW[11] = {0.00102838f, 0.00759876f, 0.03600076f, 0.10936070f,
                                     0.21300554f, 0.26601172f, 0.21300554f, 0.10936070f,
                                     0.03600076f, 0.00759876f, 0.00102838f};

// minimax atan poly, max err ~1e-6 rad (validated R7, absmax 0.0)
__device__ __forceinline__ float fast_atan2f(float y, float x) {
    float ax = fabsf(x), ay = fabsf(y);
    float mx = fmaxf(ax, ay), mn = fminf(ax, ay);
    float z = mn / mx;
    float z2 = z * z;
    float p = fmaf(z2, -0.01172120f, 0.05265332f);
    p = fmaf(z2, p, -0.11643287f);
    p = fmaf(z2, p, 0.19354346f);
    p = fmaf(z2, p, -0.33262347f);
    p = fmaf(z2, p, 0.99997726f);
    p = p * z;
    if (ay > ax) p = 1.57079632679489662f - p;
    if (x < 0.f) p = 3.14159265358979323f - p;
    return (y < 0.f) ? -p : p;
}

// ---------------- transpose: NHWC -> planar [img][b][c][row][col]; block 1600 = KLD ----------------
__global__ __launch_bounds__(256) void transpose_kernel(const float* __restrict__ xin,
                                                        const float* __restrict__ xout,
                                                        const float* __restrict__ mean,
                                                        const float* __restrict__ logvar,
                                                        float* __restrict__ Pl,
                                                        float* __restrict__ out) {
    if (blockIdx.x == 1600) {
        // KLD + seed out[0] (overwrites harness poison; work_kernel atomicAdds on top)
        float a = 0.f;
        for (int i = threadIdx.x; i < BATCH * LDIM; i += 256) {
            float m = mean[i], lv = logvar[i];
            a += -0.5f * (1.f + lv - expf(lv) - m * m) * (1.f / 32.f);
        }
        #pragma unroll
        for (int o = 32; o > 0; o >>= 1) a += __shfl_down(a, o, 64);
        __shared__ float sm[4];
        if ((threadIdx.x & 63) == 0) sm[threadIdx.x >> 6] = a;
        __syncthreads();
        if (threadIdx.x == 0) out[0] = sm[0] + sm[1] + sm[2] + sm[3];
        return;
    }
    int t = blockIdx.x * 256 + threadIdx.x;
    int colq = t % 40;
    int row  = (t / 40) % 160;
    int b    = (t / 6400) % 32;
    int img  = t / 204800;
    const float* src = img ? xout : xin;
    const float4* q = (const float4*)(src + ((size_t)(b * 160 + row) * 160 + colq * 4) * 3);
    float4 f0 = q[0], f1 = q[1], f2 = q[2];
    float* dst = Pl + (size_t)(img * 96 + b * 3) * PLANE + row * 160 + colq * 4;
    *(float4*)(dst)             = make_float4(f0.x, f0.w, f1.z, f2.y);
    *(float4*)(dst + PLANE)     = make_float4(f0.y, f1.x, f1.w, f2.z);
    *(float4*)(dst + 2 * PLANE) = make_float4(f0.z, f1.y, f2.x, f2.w);
}

// ---------------- work kernel: one item per 256-thread block ----------------
__global__ __launch_bounds__(THREADS) void work_kernel(const float* __restrict__ Pl,
                                                       float* __restrict__ out) {
    __shared__ __align__(16) float SMEM[6480];   // stft RD: 6080 fl; ssim V: 5*1296 fl
    __shared__ float sm4[4];
    const int tid = threadIdx.x;
    const int w = blockIdx.x;
    const int grp = w / 3, k3 = w % 3;
    float acc = 0.f;

    if (k3 < 2) {
        // ---- STFT item: (b, c, prg, pch) ----
        int idx = grp * 2 + k3;               // 0..3647
        int b   = idx / 114;
        int rem = idx % 114;
        int c   = rem / 38;
        int r2  = rem % 38;
        int prg = r2 / 2, pch = r2 % 2;
        int row0 = prg * 8;
        const float* base0 = Pl + (size_t)(b * 3 + c) * PLANE;
        const float* base1 = base0 + (size_t)96 * PLANE;

        // phase A: 2img * 16r * 19pc = 608 row-DFT tasks (real-input symmetry)
        for (int t = tid; t < 608; t += THREADS) {
            int pcl = t % 19;
            int r   = (t / 19) % 16;
            int img = t / 304;
            const float* rp = (img ? base1 : base0) + (row0 + r) * 160 + (pch * 19 + pcl) * 4;
            float4 q0 = *(const float4*)(rp);
            float4 q1 = *(const float4*)(rp + 4);
            float4 q2 = *(const float4*)(rp + 8);
            float x[12] = {q0.x,q0.y,q0.z,q0.w, q1.x,q1.y,q1.z,q1.w, q2.x,q2.y,q2.z,q2.w};
            float ev[5] = {x[1]+x[11], x[2]+x[10], x[3]+x[9], x[4]+x[8], x[5]+x[7]};
            float ov[5] = {x[1]-x[11], x[2]-x[10], x[3]-x[9], x[4]-x[8], x[5]-x[7]};
            #pragma unroll
            for (int vv = 0; vv < 5; ++vv) {
                int v = vv + 1;
                float re = x[0] + ((v & 1) ? -x[6] : x[6]);
                float im = 0.f;
                #pragma unroll
                for (int j = 1; j <= 5; ++j) {
                    int kk = (v * j) % 12;           // compile-time
                    re = fmaf(ev[j-1], TWC[kk], re);
                    im = fmaf(ov[j-1], TWS[kk], im);
                }
                int i2 = (((r * 5 + vv) * 2 + img) * 19 + pcl) * 2;
                *(float2*)&SMEM[i2] = make_float2(re, im);
            }
        }
        __syncthreads();

        // phase B: 190 tasks (g, vv, pcl); half-period fold, all 5 u
        if (tid < 190) {
            int pcl = tid % 19;
            int vv  = (tid / 19) % 5;
            int g   = tid / 95;
            float FR0[5] = {0,0,0,0,0}, FI0[5] = {0,0,0,0,0};
            float FR1[5] = {0,0,0,0,0}, FI1[5] = {0,0,0,0,0};
            #pragma unroll
            for (int i = 0; i < 6; ++i) {
                int rlo = 4 * g + i, rhi = rlo + 6;
                float2 a0 = *(const float2*)&SMEM[(((rlo * 5 + vv) * 2 + 0) * 19 + pcl) * 2];
                float2 a6 = *(const float2*)&SMEM[(((rhi * 5 + vv) * 2 + 0) * 19 + pcl) * 2];
                float2 b0 = *(const float2*)&SMEM[(((rlo * 5 + vv) * 2 + 1) * 19 + pcl) * 2];
                float2 b6 = *(const float2*)&SMEM[(((rhi * 5 + vv) * 2 + 1) * 19 + pcl) * 2];
                float spR0 = a0.x + a6.x, spI0 = a0.y + a6.y;
                float smR0 = a0.x - a6.x, smI0 = a0.y - a6.y;
                float spR1 = b0.x + b6.x, spI1 = b0.y + b6.y;
                float smR1 = b0.x - b6.x, smI1 = b0.y - b6.y;
                #pragma unroll
                for (int uu = 0; uu < 5; ++uu) {
                    int u = uu + 1;
                    int kk = (u * i) % 12;           // compile-time twiddle
                    float cu = TWC[kk], su = TWS[kk];
                    float sR0 = (u & 1) ? smR0 : spR0, sI0 = (u & 1) ? smI0 : spI0;
                    float sR1 = (u & 1) ? smR1 : spR1, sI1 = (u & 1) ? smI1 : spI1;
                    FR0[uu] = fmaf(cu, sR0, fmaf(-su, sI0, FR0[uu]));
                    FI0[uu] = fmaf(cu, sI0, fmaf( su, sR0, FI0[uu]));
                    FR1[uu] = fmaf(cu, sR1, fmaf(-su, sI1, FR1[uu]));
                    FI1[uu] = fmaf(cu, sI1, fmaf( su, sR1, FI1[uu]));
                }
            }
            #pragma unroll
            for (int uu = 0; uu < 5; ++uu) {
                float aI = fast_atan2f(FI0[uu], FR0[uu] + 1e-8f);
                float aO = fast_atan2f(FI1[uu], FR1[uu] + 1e-8f);
                float mI = sqrtf(FR0[uu] * FR0[uu] + FI0[uu] * FI0[uu]);
                float mO = sqrtf(FR1[uu] * FR1[uu] + FI1[uu] * FI1[uu]);
                float ff = (float)((uu + 1) * (vv + 1)) * 0.04f;
                acc += ff * (fabsf(aO - aI) + fabsf(mO - mI));
            }
        }
        acc *= 1e-4f / 32.f;
    } else {
        // ---- SSIM item: (b, c, tile of 8 output rows) ----
        int idx = grp;                         // 0..1823
        int b    = idx / 57;
        int rem  = idx % 57;
        int c    = rem / 19;
        int tile = rem % 19;
        int r0 = tile * 8;
        const float* px = Pl + (size_t)(b * 3 + c) * PLANE;
        const float* py = px + (size_t)96 * PLANE;

        // vertical 11-tap: 8*40 = 320 tasks
        for (int t = tid; t < 320; t += THREADS) {
            int orow = t / 40;
            int cbase = (t % 40) * 4;
            float ax[4] = {0,0,0,0}, ay[4] = {0,0,0,0};
            float axx[4] = {0,0,0,0}, ayy[4] = {0,0,0,0}, axy[4] = {0,0,0,0};
            #pragma unroll
            for (int kk = 0; kk < 11; ++kk) {
                int row = r0 + orow + kk;
                row = row < 160 ? row : 159;   // clamped rows feed only masked outputs
                float4 qx = *(const float4*)(px + row * 160 + cbase);
                float4 qy = *(const float4*)(py + row * 160 + cbase);
                float wg = GW[kk];
                float xs[4] = {qx.x, qx.y, qx.z, qx.w};
                float ys[4] = {qy.x, qy.y, qy.z, qy.w};
                #pragma unroll
                for (int o = 0; o < 4; ++o) {
                    ax[o]  += wg * xs[o];          ay[o]  += wg * ys[o];
                    axx[o] += wg * (xs[o]*xs[o]);  ayy[o] += wg * (ys[o]*ys[o]);
                    axy[o] += wg * (xs[o]*ys[o]);
                }
            }
            int base = orow * 160 + cbase;
            *(float4*)&SMEM[0 * 1296 + base] = make_float4(ax[0],  ax[1],  ax[2],  ax[3]);
            *(float4*)&SMEM[1 * 1296 + base] = make_float4(ay[0],  ay[1],  ay[2],  ay[3]);
            *(float4*)&SMEM[2 * 1296 + base] = make_float4(axx[0], axx[1], axx[2], axx[3]);
            *(float4*)&SMEM[3 * 1296 + base] = make_float4(ayy[0], ayy[1], ayy[2], ayy[3]);
            *(float4*)&SMEM[4 * 1296 + base] = make_float4(axy[0], axy[1], axy[2], axy[3]);
        }
        __syncthreads();

        // horizontal 11-tap + SSIM: 8*38 = 304 tasks
        for (int t = tid; t < 304; t += THREADS) {
            int orow = t / 38;
            int oc = (t % 38) * 4;
            float st[5][4];
            #pragma unroll
            for (int p = 0; p < 5; ++p) {
                float vals[16];
                #pragma unroll
                for (int q = 0; q < 4; ++q) {
                    float4 t4 = *(const float4*)&SMEM[p * 1296 + orow * 160 + oc + 4 * q];
                    vals[4*q+0] = t4.x; vals[4*q+1] = t4.y; vals[4*q+2] = t4.z; vals[4*q+3] = t4.w;
                }
                #pragma unroll
                for (int o = 0; o < 4; ++o) {
                    float s = 0.f;
                    #pragma unroll
                    for (int kk = 0; kk < 11; ++kk) s += GW[kk] * vals[o + kk];
                    st[p][o] = s;
                }
            }
            const float c1 = 1e-4f, c2 = 9e-4f;
            #pragma unroll
            for (int o = 0; o < 4; ++o) {
                if (r0 + orow < OUT_SZ && oc + o < OUT_SZ) {
                    float mx = st[0][o], my = st[1][o];
                    float vx = st[2][o] - mx * mx;
                    float vy = st[3][o] - my * my;
                    float cv = st[4][o] - mx * my;
                    float lum = (2.f * mx * my + c1) / (mx * mx + my * my + c1);
                    float cs  = (2.f * cv + c2) / (vx + vy + c2);
                    acc += lum * cs;
                }
            }
        }
        acc *= 1.f / (32.f * 150.f * 150.f * 3.f);
    }

    // block reduce -> one device-scope atomic per block
    #pragma unroll
    for (int o = 32; o > 0; o >>= 1) acc += __shfl_down(acc, o, 64);
    if ((tid & 63) == 0) sm4[tid >> 6] = acc;
    __syncthreads();
    if (tid == 0) atomicAdd(out, sm4[0] + sm4[1] + sm4[2] + sm4[3]);
}

extern "C" void kernel_launch(void* const* d_in, const int* in_sizes, int n_in,
                              void* d_out, int out_size, void* d_ws, size_t ws_size,
                              hipStream_t stream) {
    const float* mean   = (const float*)d_in[0];
    const float* logvar = (const float*)d_in[1];
    const float* xin    = (const float*)d_in[2];
    const float* xout   = (const float*)d_in[3];
    float* out = (float*)d_out;
    float* Pl = (float*)d_ws;                    // 19.7 MB planes (ws proven >= 46.7 MB)

    transpose_kernel<<<1601, 256, 0, stream>>>(xin, xout, mean, logvar, Pl, out);
    work_kernel<<<N_WORK, THREADS, 0, stream>>>(Pl, out);
}